// Round 1
// 198.359 us; speedup vs baseline: 1.0083x; 1.0083x over previous
//
#include <hip/hip_runtime.h>
#include <math.h>

#define NANCH 896
#define MAXD 64
#define NS 14   // 896 / 64 slots per lane

__device__ __forceinline__ float selv17(const float d[17], int c) {
    float v = d[0];
#pragma unroll
    for (int k = 1; k < 17; ++k) v = (c == k) ? d[k] : v;
    return v;
}

// One WAVE per batch, 4 independent waves/block, no barriers.
// Key change vs previous version: the box/anchor load gate is a SIGN TEST on
// the raw score (sigmoid(x)>=0.5 <=> x>=0, exact), so box loads issue one
// compare after the score loads return — the 14-deep expf sigmoid chain now
// overlaps the box-load latency instead of serializing in front of it.
__global__ __launch_bounds__(256, 2) void blaze_wave_kernel(
    const float* __restrict__ raw_boxes,   // [B,896,16]
    const float* __restrict__ raw_scores,  // [B,896]
    const float* __restrict__ anchors,     // [896,4]
    const float* __restrict__ tmat,        // [B,8]
    const int* __restrict__ hptr,
    const int* __restrict__ wptr,
    float* __restrict__ out,               // [B,64,17]
    int B)
{
    __shared__ float sdet[4][17];          // per-wave det broadcast for fill tail
    const int lane = threadIdx.x & 63;
    const int wv   = threadIdx.x >> 6;
    const int b    = blockIdx.x * 4 + wv;
    if (b >= B) return;

    const float* rb = raw_boxes  + (size_t)b * (NANCH * 16);
    const float* rs = raw_scores + (size_t)b * NANCH;
    const float inv = 1.f / 128.f;

    // ---- uniform per-batch params issued in the same up-front load burst ----
    const float* M = tmat + (size_t)b * 8;
    const float m0 = M[0], m1 = M[1], m3 = M[3];
    const float m4 = M[4], m5 = M[5], m7 = M[7];
    const float hf = (float)(*hptr);
    const float wf = (float)(*wptr);

    // ---- Phase 1: ALL score loads issued back-to-back ----
    float xv[NS];
#pragma unroll
    for (int j = 0; j < NS; ++j) xv[j] = rs[lane + 64 * j];

    // ---- Phase 2: box/anchor loads gated by SIGN only (no expf on the
    //      critical path). Inactive lanes alias row 0's line (no extra traffic).
    bool  act[NS];
    float4 r0v[NS], anv[NS];
#pragma unroll
    for (int j = 0; j < NS; ++j) {
        act[j] = (xv[j] >= 0.f);           // == sigmoid(clamp(x)) >= 0.5, exact
        const int a2 = act[j] ? (lane + 64 * j) : 0;
        r0v[j] = *(const float4*)(rb + a2 * 16);
        anv[j] = *(const float4*)(anchors + a2 * 4);
    }

    // ---- sigmoid now overlaps the in-flight box loads ----
    float rem[NS];
#pragma unroll
    for (int j = 0; j < NS; ++j) {
        float x = fminf(fmaxf(xv[j], -100.f), 100.f);
        float s = 1.f / (1.f + expf(-x));  // only x>=0 side consumed
        rem[j] = act[j] ? s : -1.f;
    }

    // ---- decode boxes for all slots unconditionally (rem gates use);
    //      per-slot area is loop-invariant -> precompute once ----
    float b0[NS], b1[NS], b2[NS], b3[NS], ar[NS];
#pragma unroll
    for (int j = 0; j < NS; ++j) {
        float xc = r0v[j].x * inv * anv[j].z + anv[j].x;
        float yc = r0v[j].y * inv * anv[j].w + anv[j].y;
        float ww = r0v[j].z * inv * anv[j].z;
        float hh = r0v[j].w * inv * anv[j].w;
        b0[j] = yc - hh * 0.5f; b1[j] = xc - ww * 0.5f;
        b2[j] = yc + hh * 0.5f; b3[j] = xc + ww * 0.5f;
        ar[j] = fmaxf(b2[j] - b0[j], 0.f) * fmaxf(b3[j] - b1[j], 0.f);
    }

    float* ob = out + (size_t)b * (MAXD * 17);

    int iter = 0;
    while (true) {
        // ---- argmax(rem), first-index tie-break ----
        float bv = -2.f; int bi = 1 << 30;
#pragma unroll
        for (int j = 0; j < NS; ++j) {
            if (rem[j] > bv) { bv = rem[j]; bi = lane + 64 * j; }
        }
#pragma unroll
        for (int s2 = 32; s2 >= 1; s2 >>= 1) {
            float ov = __shfl_xor(bv, s2, 64);
            int   oi = __shfl_xor(bi, s2, 64);
            if (ov > bv || (ov == bv && oi < bi)) { bv = ov; bi = oi; }
        }

        if (bv <= 0.f) {
            int n = (MAXD - iter) * 17;
            float* op = ob + iter * 17;
            for (int e = lane; e < n; e += 64) op[e] = 0.f;
            break;
        }

        // ---- broadcast best box from owning lane/slot (registers only) ----
        const int bl = bi & 63, bj = bi >> 6;
        float vb0 = b0[0], vb1 = b1[0], vb2 = b2[0], vb3 = b3[0];
#pragma unroll
        for (int j = 1; j < NS; ++j) {
            if (bj == j) { vb0 = b0[j]; vb1 = b1[j]; vb2 = b2[j]; vb3 = b3[j]; }
        }
        const float bby0 = __shfl(vb0, bl, 64);
        const float bbx0 = __shfl(vb1, bl, 64);
        const float bby1 = __shfl(vb2, bl, 64);
        const float bbx1 = __shfl(vb3, bl, 64);
        const float a1 = fmaxf(bby1 - bby0, 0.f) * fmaxf(bbx1 - bbx0, 0.f);

        float acc[16];
#pragma unroll
        for (int c = 0; c < 16; ++c) acc[c] = 0.f;
        float wsum = 0.f;
        bool anyov = false;

#pragma unroll
        for (int j = 0; j < NS; ++j) {
            if (rem[j] > 0.f) {
                float yA = fmaxf(bby0, b0[j]);
                float xA = fmaxf(bbx0, b1[j]);
                float yB = fminf(bby1, b2[j]);
                float xB = fminf(bbx1, b3[j]);
                float inter = fmaxf(yB - yA, 0.f) * fmaxf(xB - xA, 0.f);
                float iou = inter / fmaxf(a1 + ar[j] - inter, 1e-6f);
                if (iou > 0.3f) {
                    anyov = true;
                    float wj = rem[j];          // rem>0 ==> rem == score
                    rem[j] = -1.f;
                    wsum += wj;
                    acc[0] += b0[j] * wj; acc[1] += b1[j] * wj;
                    acc[2] += b2[j] * wj; acc[3] += b3[j] * wj;
                    // keypoints refetched only for overlapped boxes (rare, hot line)
                    const int a = lane + 64 * j;
                    float4 an = *(const float4*)(anchors + a * 4);
                    const float* rp = rb + a * 16;
                    float4 r1 = *(const float4*)(rp + 4);
                    float4 r2 = *(const float4*)(rp + 8);
                    float4 r3 = *(const float4*)(rp + 12);
                    acc[4]  += (r1.x * inv * an.z + an.x) * wj;
                    acc[5]  += (r1.y * inv * an.w + an.y) * wj;
                    acc[6]  += (r1.z * inv * an.z + an.x) * wj;
                    acc[7]  += (r1.w * inv * an.w + an.y) * wj;
                    acc[8]  += (r2.x * inv * an.z + an.x) * wj;
                    acc[9]  += (r2.y * inv * an.w + an.y) * wj;
                    acc[10] += (r2.z * inv * an.z + an.x) * wj;
                    acc[11] += (r2.w * inv * an.w + an.y) * wj;
                    acc[12] += (r3.x * inv * an.z + an.x) * wj;
                    acc[13] += (r3.y * inv * an.w + an.y) * wj;
                    acc[14] += (r3.z * inv * an.z + an.x) * wj;
                    acc[15] += (r3.w * inv * an.w + an.y) * wj;
                }
            }
        }

        bool stuck = (__ballot(anyov) == 0ull);  // nothing removed -> fixed point

        float det[17];
        if (!stuck) {
#pragma unroll
            for (int s2 = 32; s2 >= 1; s2 >>= 1) {
                wsum += __shfl_xor(wsum, s2, 64);
#pragma unroll
                for (int c = 0; c < 16; ++c) acc[c] += __shfl_xor(acc[c], s2, 64);
            }
            float dnm = fmaxf(wsum, 1e-6f);
#pragma unroll
            for (int c = 0; c < 16; ++c) det[c] = acc[c] / dnm;
        } else {
#pragma unroll
            for (int c = 0; c < 16; ++c) det[c] = 0.f;
        }
        det[16] = bv;

        // ---- project + rescale ----
        {
            const int xi[8] = { 1, 3, 4, 6, 8, 10, 12, 14 };
            const int yi[8] = { 0, 2, 5, 7, 9, 11, 13, 15 };
#pragma unroll
            for (int k = 0; k < 8; ++k) {
                float x = det[xi[k]], y = det[yi[k]];
                det[xi[k]] = (x * m0 + y * m1 + m3) * wf;
                det[yi[k]] = (x * m4 + y * m5 + m7) * hf;
            }
        }

        if (stuck) {
            // det is wave-uniform (post-reduction). Cache the 17 floats in LDS
            // once, then fill remaining rows with 1 ds_read + incremental
            // mod-17 per element instead of a 16-deep cndmask chain + idiv.
            if (lane < 17) sdet[wv][lane] = selv17(det, lane);
            int n = (MAXD - iter) * 17;
            float* op = ob + iter * 17;
            int c = lane % 17;
            for (int e = lane; e < n; e += 64) {
                op[e] = sdet[wv][c];
                c += 13; if (c >= 17) c -= 17;   // (e+64) % 17
            }
            break;
        } else {
            if (lane < 17) ob[iter * 17 + lane] = selv17(det, lane);
            ++iter;
            if (iter == MAXD) break;
        }
    }
}

extern "C" void kernel_launch(void* const* d_in, const int* in_sizes, int n_in,
                              void* d_out, int out_size, void* d_ws, size_t ws_size,
                              hipStream_t stream) {
    (void)n_in; (void)out_size; (void)d_ws; (void)ws_size;
    const float* raw_boxes  = (const float*)d_in[0];
    const float* raw_scores = (const float*)d_in[1];
    const float* anchors    = (const float*)d_in[2];
    const float* tmat       = (const float*)d_in[3];
    const int*   hptr       = (const int*)d_in[4];
    const int*   wptr       = (const int*)d_in[5];
    float* out = (float*)d_out;

    const int B = in_sizes[0] / (NANCH * 16);
    blaze_wave_kernel<<<(B + 3) / 4, 256, 0, stream>>>(raw_boxes, raw_scores, anchors,
                                                       tmat, hptr, wptr, out, B);
}

// Round 2
// 184.451 us; speedup vs baseline: 1.0843x; 1.0754x over previous
//
#include <hip/hip_runtime.h>
#include <math.h>

#define NANCH 896
#define MAXD 64
#define NS 14   // 896 / 64 slots per lane

// One WAVE per batch, 4 independent waves/block, no barriers (per-wave LDS only).
//
// Round-2 restructure of the serial NMS loop (the kernel is VALU/DS-bound, not
// memory-bound: ~105MB traffic = 17us but kernel ~60us at 2 waves/SIMD):
//  (a) single-contributor fast path replaces the 17-channel 6-step butterfly
//      (102 ds_bpermute -> 17) -- bit-exact because the butterfly only adds +0
//  (b) IoU divide gated on inter>0 (inter==0 => iou==0, exact)
//  (c) divide/project/store lane-distributed: lane c owns channel c -> ONE
//      divide instead of 17, 6-op projection instead of 48, no selv17 chains
//  (d) best-box broadcast via per-wave LDS box table (1 ds_read_b128 broadcast
//      instead of a 52-op cndmask chain + 4 shfl)
__global__ __launch_bounds__(256, 2) void blaze_wave_kernel(
    const float* __restrict__ raw_boxes,   // [B,896,16]
    const float* __restrict__ raw_scores,  // [B,896]
    const float* __restrict__ anchors,     // [896,4]
    const float* __restrict__ tmat,        // [B,8]
    const int* __restrict__ hptr,
    const int* __restrict__ wptr,
    float* __restrict__ out,               // [B,64,17]
    int B)
{
    __shared__ float4 sbox[4][NANCH];      // 57344 B: decoded boxes per wave
    __shared__ float  sdet[4][17];         // det broadcast for stuck-fill tail

    const int lane = threadIdx.x & 63;
    const int wv   = threadIdx.x >> 6;
    const int b    = blockIdx.x * 4 + wv;
    if (b >= B) return;

    const float* rb = raw_boxes  + (size_t)b * (NANCH * 16);
    const float* rs = raw_scores + (size_t)b * NANCH;
    const float inv = 1.f / 128.f;

    // ---- uniform per-batch params in the up-front load burst ----
    const float* M = tmat + (size_t)b * 8;
    const float m0 = M[0], m1 = M[1], m3 = M[3];
    const float m4 = M[4], m5 = M[5], m7 = M[7];
    const float hf = (float)(*hptr);
    const float wf = (float)(*wptr);

    // ---- Phase 1: ALL score loads issued back-to-back ----
    float xv[NS];
#pragma unroll
    for (int j = 0; j < NS; ++j) xv[j] = rs[lane + 64 * j];

    // ---- Phase 2: box/anchor loads gated by SIGN only (sigmoid>=0.5 <=> x>=0) ----
    bool  act[NS];
    float4 r0v[NS], anv[NS];
#pragma unroll
    for (int j = 0; j < NS; ++j) {
        act[j] = (xv[j] >= 0.f);
        const int a2 = act[j] ? (lane + 64 * j) : 0;
        r0v[j] = *(const float4*)(rb + a2 * 16);
        anv[j] = *(const float4*)(anchors + a2 * 4);
    }

    // ---- sigmoid overlaps the in-flight box loads ----
    float rem[NS];
#pragma unroll
    for (int j = 0; j < NS; ++j) {
        float x = fminf(fmaxf(xv[j], -100.f), 100.f);
        float s = 1.f / (1.f + expf(-x));
        rem[j] = act[j] ? s : -1.f;
    }

    // ---- decode all slots; area precomputed; boxes mirrored to LDS ----
    float b0[NS], b1[NS], b2[NS], b3[NS], ar[NS];
#pragma unroll
    for (int j = 0; j < NS; ++j) {
        float xc = r0v[j].x * inv * anv[j].z + anv[j].x;
        float yc = r0v[j].y * inv * anv[j].w + anv[j].y;
        float ww = r0v[j].z * inv * anv[j].z;
        float hh = r0v[j].w * inv * anv[j].w;
        b0[j] = yc - hh * 0.5f; b1[j] = xc - ww * 0.5f;
        b2[j] = yc + hh * 0.5f; b3[j] = xc + ww * 0.5f;
        ar[j] = fmaxf(b2[j] - b0[j], 0.f) * fmaxf(b3[j] - b1[j], 0.f);
        sbox[wv][lane + 64 * j] = make_float4(b0[j], b1[j], b2[j], b3[j]);
    }

    float* ob = out + (size_t)b * (MAXD * 17);
    // x-channels: {1,3,4,6,8,10,12,14} -> bitmask 0x555A; partner = c^1
    const bool isx = (lane < 16) && ((0x555Au >> lane) & 1u);

    int iter = 0;
    while (true) {
        // ---- argmax(rem), first-index tie-break ----
        float bv = -2.f; int bi = 1 << 30;
#pragma unroll
        for (int j = 0; j < NS; ++j) {
            if (rem[j] > bv) { bv = rem[j]; bi = lane + 64 * j; }
        }
#pragma unroll
        for (int s2 = 32; s2 >= 1; s2 >>= 1) {
            float ov = __shfl_xor(bv, s2, 64);
            int   oi = __shfl_xor(bi, s2, 64);
            if (ov > bv || (ov == bv && oi < bi)) { bv = ov; bi = oi; }
        }

        if (bv <= 0.f) {
            int n = (MAXD - iter) * 17;
            float* op = ob + iter * 17;
            for (int e = lane; e < n; e += 64) op[e] = 0.f;
            break;
        }

        // ---- best box: one broadcast LDS read (all lanes same address) ----
        float4 bb = sbox[wv][bi];
        const float bby0 = bb.x, bbx0 = bb.y, bby1 = bb.z, bbx1 = bb.w;
        const float a1 = fmaxf(bby1 - bby0, 0.f) * fmaxf(bbx1 - bbx0, 0.f);

        float acc[16];
#pragma unroll
        for (int c = 0; c < 16; ++c) acc[c] = 0.f;
        float wsum = 0.f;
        bool anyov = false;

        // ---- overlap scan: divide only when inter>0 (exact gating) ----
#pragma unroll
        for (int j = 0; j < NS; ++j) {
            float yA = fmaxf(bby0, b0[j]);
            float xA = fmaxf(bbx0, b1[j]);
            float yB = fminf(bby1, b2[j]);
            float xB = fminf(bbx1, b3[j]);
            float inter = fmaxf(yB - yA, 0.f) * fmaxf(xB - xA, 0.f);
            if (inter > 0.f) {
                float iou = inter / fmaxf(a1 + ar[j] - inter, 1e-6f);
                if (iou > 0.3f && rem[j] > 0.f) {
                    anyov = true;
                    float wj = rem[j];          // rem>0 ==> rem == score
                    rem[j] = -1.f;
                    wsum += wj;
                    acc[0] += b0[j] * wj; acc[1] += b1[j] * wj;
                    acc[2] += b2[j] * wj; acc[3] += b3[j] * wj;
                    // keypoints refetched only for overlapped boxes (hot lines)
                    const int a = lane + 64 * j;
                    float4 an = *(const float4*)(anchors + a * 4);
                    const float* rp = rb + a * 16;
                    float4 r1 = *(const float4*)(rp + 4);
                    float4 r2 = *(const float4*)(rp + 8);
                    float4 r3 = *(const float4*)(rp + 12);
                    acc[4]  += (r1.x * inv * an.z + an.x) * wj;
                    acc[5]  += (r1.y * inv * an.w + an.y) * wj;
                    acc[6]  += (r1.z * inv * an.z + an.x) * wj;
                    acc[7]  += (r1.w * inv * an.w + an.y) * wj;
                    acc[8]  += (r2.x * inv * an.z + an.x) * wj;
                    acc[9]  += (r2.y * inv * an.w + an.y) * wj;
                    acc[10] += (r2.z * inv * an.z + an.x) * wj;
                    acc[11] += (r2.w * inv * an.w + an.y) * wj;
                    acc[12] += (r3.x * inv * an.z + an.x) * wj;
                    acc[13] += (r3.y * inv * an.w + an.y) * wj;
                    acc[14] += (r3.z * inv * an.z + an.x) * wj;
                    acc[15] += (r3.w * inv * an.w + an.y) * wj;
                }
            }
        }

        const unsigned long long mm = __ballot(anyov);
        const bool stuck = (mm == 0ull);

        float tot[16]; float ws;
        if (stuck) {
            // fixed point: reference blends zeros (denom=1e-6) -> tot=0, ws=0
#pragma unroll
            for (int c = 0; c < 16; ++c) tot[c] = 0.f;
            ws = 0.f;
        } else if (__popcll(mm) == 1) {
            // FAST PATH: one contributing lane -> broadcast its partials.
            // Bit-exact vs butterfly: all other lanes hold +0 and x+0==x.
            const int src = (int)__ffsll((long long)mm) - 1;
#pragma unroll
            for (int c = 0; c < 16; ++c) tot[c] = __shfl(acc[c], src, 64);
            ws = __shfl(wsum, src, 64);
        } else {
            // general path (rare): full butterfly, identical tree as before
#pragma unroll
            for (int s2 = 32; s2 >= 1; s2 >>= 1) {
                wsum += __shfl_xor(wsum, s2, 64);
#pragma unroll
                for (int c = 0; c < 16; ++c) acc[c] += __shfl_xor(acc[c], s2, 64);
            }
#pragma unroll
            for (int c = 0; c < 16; ++c) tot[c] = acc[c];
            ws = wsum;
        }

        // ---- lane-distributed divide + project: lane c owns channel c ----
        float q = tot[0];
#pragma unroll
        for (int k = 1; k < 16; ++k) q = (lane == k) ? tot[k] : q;
        const float dnm = fmaxf(ws, 1e-6f);
        q = q / dnm;                               // ONE divide per lane
        const float p = __shfl(q, lane ^ 1, 64);   // x/y partner channel
        float detc;
        if (lane >= 16) detc = bv;                 // score channel (x1.0 scale)
        else detc = isx ? (q * m0 + p * m1 + m3) * wf
                        : (p * m4 + q * m5 + m7) * hf;

        if (stuck) {
            // det is identical for all remaining rows; lane c holds det[c]
            if (lane < 17) sdet[wv][lane] = detc;
            int n = (MAXD - iter) * 17;
            float* op = ob + iter * 17;
            int c = lane % 17;
            for (int e = lane; e < n; e += 64) {
                op[e] = sdet[wv][c];
                c += 13; if (c >= 17) c -= 17;     // (e+64) % 17
            }
            break;
        } else {
            if (lane < 17) ob[iter * 17 + lane] = detc;
            ++iter;
            if (iter == MAXD) break;
        }
    }
}

extern "C" void kernel_launch(void* const* d_in, const int* in_sizes, int n_in,
                              void* d_out, int out_size, void* d_ws, size_t ws_size,
                              hipStream_t stream) {
    (void)n_in; (void)out_size; (void)d_ws; (void)ws_size;
    const float* raw_boxes  = (const float*)d_in[0];
    const float* raw_scores = (const float*)d_in[1];
    const float* anchors    = (const float*)d_in[2];
    const float* tmat       = (const float*)d_in[3];
    const int*   hptr       = (const int*)d_in[4];
    const int*   wptr       = (const int*)d_in[5];
    float* out = (float*)d_out;

    const int B = in_sizes[0] / (NANCH * 16);
    blaze_wave_kernel<<<(B + 3) / 4, 256, 0, stream>>>(raw_boxes, raw_scores, anchors,
                                                       tmat, hptr, wptr, out, B);
}